// Round 3
// baseline (105226.721 us; speedup 1.0000x reference)
//
#include <hip/hip_runtime.h>
#include <cstdint>
#include <cstddef>

#define NV    32768
#define EMB   512
#define DEG   32
#define NC    50
#define H3DIM 281
#define MT    4096
#define GROWS 32767            // N-1 gumbel rows

// ---------------- threefry2x32, key = jax.random.key(42) -> (0, 42) ----------------
__device__ __forceinline__ void threefry(unsigned x0, unsigned x1,
                                         unsigned& y0, unsigned& y1) {
  const unsigned ks0 = 0u, ks1 = 42u, ks2 = 0x1BD11BDAu ^ 42u;
  x0 += ks0; x1 += ks1;
#define TFR(r) { x0 += x1; x1 = (x1 << (r)) | (x1 >> (32 - (r))); x1 ^= x0; }
  TFR(13) TFR(15) TFR(26) TFR(6)  x0 += ks1; x1 += ks2 + 1u;
  TFR(17) TFR(29) TFR(16) TFR(24) x0 += ks2; x1 += ks0 + 2u;
  TFR(13) TFR(15) TFR(26) TFR(6)  x0 += ks0; x1 += ks1 + 3u;
  TFR(17) TFR(29) TFR(16) TFR(24) x0 += ks1; x1 += ks2 + 4u;
  TFR(13) TFR(15) TFR(26) TFR(6)  x0 += ks2; x1 += ks0 + 5u;
#undef TFR
  y0 = x0; y1 = x1;
}

// partitionable threefry (jax >= 0.5 default): bits(i) = xor of threefry(key, (0, i))
__device__ __forceinline__ float gumbel_at(unsigned idx) {
  unsigned y0, y1;
  threefry(0u, idx, y0, y1);
  unsigned bits = y0 ^ y1;
  unsigned fb = (bits >> 9) | 0x3F800000u;
  float f = __uint_as_float(fb) - 1.0f;
  float u = fmaxf(f, 1.17549435e-38f);
  return -logf(-logf(u));
}

// ---------------- fp32 tiled GEMM: C = act(A[MxK] @ W[KxN] + b) ----------------
// k-ascending single-accumulator FMA chain — MUST stay byte-identical across rounds
// (argmax exactness depends on stable logits bits).
#define TILE 64
#define BK   16
__global__ __launch_bounds__(256) void gemm_bias_act(
    const float* __restrict__ A, const float* __restrict__ W,
    const float* __restrict__ bias, float* __restrict__ C,
    int M, int N, int K, int act) {
  __shared__ float As[BK][TILE + 1];
  __shared__ float Bs[BK][TILE];
  int tid = threadIdx.x;
  int bm = blockIdx.y * TILE;
  int bn = blockIdx.x * TILE;
  int tx = tid & 15, ty = tid >> 4;
  int ar = tid >> 2;
  int ac = (tid & 3) * 4;
  int br = tid >> 4;
  int bc = (tid & 15) * 4;
  float acc[4][4] = {{0.f,0.f,0.f,0.f},{0.f,0.f,0.f,0.f},{0.f,0.f,0.f,0.f},{0.f,0.f,0.f,0.f}};

  for (int k0 = 0; k0 < K; k0 += BK) {
    {
      int gk = k0 + ac;
      const float* ap = A + (size_t)(bm + ar) * K + gk;
      float a0, a1, a2, a3;
      if (((K & 3) == 0) && (gk + 3 < K)) {
        float4 av = *(const float4*)ap;
        a0 = av.x; a1 = av.y; a2 = av.z; a3 = av.w;
      } else {
        a0 = (gk + 0 < K) ? ap[0] : 0.f;
        a1 = (gk + 1 < K) ? ap[1] : 0.f;
        a2 = (gk + 2 < K) ? ap[2] : 0.f;
        a3 = (gk + 3 < K) ? ap[3] : 0.f;
      }
      As[ac + 0][ar] = a0; As[ac + 1][ar] = a1;
      As[ac + 2][ar] = a2; As[ac + 3][ar] = a3;
    }
    {
      int gr = k0 + br;
      int gc = bn + bc;
      const float* bp = W + (size_t)gr * N + gc;
      float b0 = 0.f, b1 = 0.f, b2 = 0.f, b3 = 0.f;
      if (gr < K) {
        if (((N & 3) == 0) && (gc + 3 < N)) {
          float4 bv = *(const float4*)bp;
          b0 = bv.x; b1 = bv.y; b2 = bv.z; b3 = bv.w;
        } else {
          b0 = (gc + 0 < N) ? bp[0] : 0.f;
          b1 = (gc + 1 < N) ? bp[1] : 0.f;
          b2 = (gc + 2 < N) ? bp[2] : 0.f;
          b3 = (gc + 3 < N) ? bp[3] : 0.f;
        }
      }
      Bs[br][bc + 0] = b0; Bs[br][bc + 1] = b1;
      Bs[br][bc + 2] = b2; Bs[br][bc + 3] = b3;
    }
    __syncthreads();
#pragma unroll
    for (int kk = 0; kk < BK; ++kk) {
      float a[4], b[4];
#pragma unroll
      for (int i = 0; i < 4; ++i) a[i] = As[kk][ty * 4 + i];
#pragma unroll
      for (int j = 0; j < 4; ++j) b[j] = Bs[kk][tx * 4 + j];
#pragma unroll
      for (int i = 0; i < 4; ++i)
#pragma unroll
        for (int j = 0; j < 4; ++j)
          acc[i][j] = fmaf(a[i], b[j], acc[i][j]);
    }
    __syncthreads();
  }
#pragma unroll
  for (int i = 0; i < 4; ++i) {
    int row = bm + ty * 4 + i;
#pragma unroll
    for (int j = 0; j < 4; ++j) {
      int cn = bn + tx * 4 + j;
      if (cn < N) {
        float v = acc[i][j] + bias[cn];
        if (act) v = (v >= 0.f) ? v : 0.01f * v;
        C[(size_t)row * N + cn] = v;
      }
    }
  }
}

// ---------------- init: colors=-1, used=0, counters=0 ----------------
__global__ void init_kernel(int* __restrict__ colors,
                            unsigned long long* __restrict__ used,
                            int* __restrict__ icnt) {
  int i = blockIdx.x * 256 + threadIdx.x;
  if (i < NV) colors[i] = -1;
  if (i == 0) { *used = 0ull; icnt[0] = 0; icnt[1] = 0; }
}

// ---------------- inverse permutation ----------------
__global__ void pos_kernel(const int* __restrict__ order, int* __restrict__ pos) {
  int i = blockIdx.x * 256 + threadIdx.x;
  if (i < NV) pos[order[i]] = i;
}

// ---------------- y[p][c] = logits[order[p]][c] + gumbel[(p-1)*NC + c] ----------------
__global__ void yadd_kernel(const float* __restrict__ logit,
                            const int* __restrict__ order,
                            float* __restrict__ y) {
  int tid = blockIdx.x * 256 + threadIdx.x;
  if (tid >= GROWS * NC) return;
  int p = tid / NC + 1;
  int c = tid - (p - 1) * NC;
  int v = order[p];
  y[p * NC + c] = logit[v * NC + c] + gumbel_at((unsigned)tid);
}

// ---------------- dataflow coloring: 1024 single-wave blocks ----------------
// Block b owns positions [32b, 32b+32); deps point only to <= block IDs
// (decoupled-lookback forward-progress pattern). Colors via agent-scope atomics.
__global__ __launch_bounds__(64) void color_dataflow(
    const float* __restrict__ y, const int* __restrict__ adj,
    const int* __restrict__ order, const int* __restrict__ pos,
    int* colors, unsigned long long* used) {
  int lane = threadIdx.x;
  int p0 = blockIdx.x * 32;
  unsigned long long um = 0ull;
  for (int i = 0; i < 32; ++i) {
    int p = p0 + i;
    int v = order[p];
    int chosen = 0;
    if (p > 0) {
      float yv = (lane < NC) ? y[p * NC + lane] : -INFINITY;
      int u = 0; bool need = false;
      if (lane < DEG) { u = adj[v * DEG + lane]; need = (pos[u] < p); }
      int c = -1;
      if (need) {
        c = __hip_atomic_load(colors + u, __ATOMIC_ACQUIRE, __HIP_MEMORY_SCOPE_AGENT);
        int guard = 0;
        while (c < 0 && guard < (1 << 22)) {  // bounded spin: no infinite hang
          __builtin_amdgcn_s_sleep(1);
          c = __hip_atomic_load(colors + u, __ATOMIC_ACQUIRE, __HIP_MEMORY_SCOPE_AGENT);
          ++guard;
        }
      }
      unsigned long long bits = (need && c >= 0) ? (1ull << c) : 0ull;
#pragma unroll
      for (int off = 1; off < 64; off <<= 1) bits |= __shfl_xor(bits, off);
      bool masked = (bits >> lane) & 1ull;
      float ymv = (lane < NC && !masked) ? yv : -INFINITY;
      float m = ymv;
#pragma unroll
      for (int off = 1; off < 64; off <<= 1) m = fmaxf(m, __shfl_xor(m, off));
      unsigned long long eq = __ballot(ymv == m);
      chosen = __ffsll(eq) - 1;  // first-index tie-break, matches jnp.argmax
    }
    if (lane == 0)
      __hip_atomic_store(colors + v, chosen, __ATOMIC_RELEASE, __HIP_MEMORY_SCOPE_AGENT);
    um |= 1ull << chosen;
  }
  if (lane == 0) atomicOr(used, um);
}

// ---------------- parallel logp reconstruction (one wave per position) ----------------
__global__ __launch_bounds__(256) void logp_kernel(
    const float* __restrict__ logit, const int* __restrict__ adj,
    const int* __restrict__ order, const int* __restrict__ pos,
    const int* __restrict__ colors, float* __restrict__ term) {
  int wid = blockIdx.x * 4 + (threadIdx.x >> 6);
  int lane = threadIdx.x & 63;
  int p = wid + 1;
  if (p >= NV) return;
  int v = order[p];
  int cchosen = colors[v];
  unsigned long long bits = 0ull;
  if (lane < DEG) {
    int u = adj[v * DEG + lane];
    if (pos[u] < p) bits = 1ull << colors[u];  // color at time p == final color
  }
#pragma unroll
  for (int off = 1; off < 64; off <<= 1) bits |= __shfl_xor(bits, off);
  bool masked = (bits >> lane) & 1ull;
  float xv = (lane < NC) ? logit[v * NC + lane] : -INFINITY;
  float x = (lane < NC && !masked) ? xv : -INFINITY;
  float xm = x;
#pragma unroll
  for (int off = 1; off < 64; off <<= 1) xm = fmaxf(xm, __shfl_xor(xm, off));
  float ex = expf(x - xm);  // -inf -> 0
  float S = ex;
#pragma unroll
  for (int off = 1; off < 64; off <<= 1) S += __shfl_xor(S, off);
  float ec = __shfl(ex, cchosen);
  float pr = ec / S;
  if (lane == 0) term[p - 1] = logf(pr + 1e-8f) - logf(1e-8f);
}

// ---------------- deterministic sum of 32767 terms ----------------
__global__ __launch_bounds__(256) void sum_kernel(const float* __restrict__ term,
                                                  float* __restrict__ scal) {
  __shared__ float sm[256];
  float s = 0.f;
  for (int i = threadIdx.x; i < GROWS; i += 256) s += term[i];
  sm[threadIdx.x] = s;
  __syncthreads();
  for (int st = 128; st > 0; st >>= 1) {
    if (threadIdx.x < st) sm[threadIdx.x] += sm[threadIdx.x + st];
    __syncthreads();
  }
  if (threadIdx.x == 0) scal[0] = sm[0];
}

// ---------------- violation count ----------------
__global__ void violation_kernel(const int* __restrict__ col,
                                 const int* __restrict__ adj,
                                 int* __restrict__ cnt) {
  int idx = blockIdx.x * 256 + threadIdx.x;  // exactly NV*DEG threads
  int v = idx >> 5;
  int same = (col[adj[idx]] == col[v]) ? 1 : 0;
  unsigned long long b = __ballot(same);
  if ((threadIdx.x & 63) == 0) atomicAdd(cnt, __popcll(b));
}

// ---------------- write colors + loss ----------------
__global__ void final_kernel(const int* __restrict__ colors,
                             const float* __restrict__ scal,
                             const unsigned long long* __restrict__ used,
                             const int* __restrict__ icnt,
                             float* __restrict__ out) {
  int i = blockIdx.x * 256 + threadIdx.x;
  if (i < NV) out[i] = (float)colors[i];
  if (i == NV) {
    float logp = scal[0];
    float nused = (float)__popcll(*used);
    float ratio = (float)icnt[1] / 1048576.0f;  // exact: count / 2^20
    float cost = nused + ratio * 100.0f;
    out[NV] = cost * (logp / 32768.0f);
  }
}

// ---------------- launch ----------------
extern "C" void kernel_launch(void* const* d_in, const int* in_sizes, int n_in,
                              void* d_out, int out_size, void* d_ws, size_t ws_size,
                              hipStream_t stream) {
  const float* emb  = (const float*)d_in[0];
  const int*   adj  = (const int*)d_in[1];
  const int*   ord  = (const int*)d_in[2];
  const float* W1   = (const float*)d_in[3];
  const float* b1   = (const float*)d_in[4];
  const float* W2   = (const float*)d_in[5];
  const float* b2   = (const float*)d_in[6];
  const float* W3   = (const float*)d_in[7];
  const float* b3   = (const float*)d_in[8];
  const float* W4   = (const float*)d_in[9];
  const float* b4   = (const float*)d_in[10];
  float* out = (float*)d_out;

  // workspace (< 28 MB): GEMM tiles first, then their regions are reused
  char* ws = (char*)d_ws;
  float* logit = (float*)(ws);                               // 6.55 MB, lives whole run
  float* H1t   = (float*)(ws + (size_t)7  * 1024 * 1024);    // 8 MB (GEMM phase)
  float* H2t   = (float*)(ws + (size_t)15 * 1024 * 1024);    // 8 MB (GEMM phase)
  float* H3t   = (float*)(ws + (size_t)23 * 1024 * 1024);    // 4.6 MB (GEMM phase)
  // after GEMMs, H1t/H2t regions are dead -> reuse:
  float* y     = (float*)(ws + (size_t)7  * 1024 * 1024);    // 6.55 MB (in old H1t)
  int*   col32 = (int*)  (ws + (size_t)15 * 1024 * 1024);            // 128 KB
  int*   pos   = (int*)  (ws + (size_t)15 * 1024 * 1024 + 131072);   // 128 KB
  float* term  = (float*)(ws + (size_t)15 * 1024 * 1024 + 262144);   // 128 KB
  float* scal  = (float*)(ws + (size_t)15 * 1024 * 1024 + 458752);
  unsigned long long* used = (unsigned long long*)(ws + (size_t)15 * 1024 * 1024 + 458752 + 64);
  int*   icnt  = (int*)  (ws + (size_t)15 * 1024 * 1024 + 458752 + 128);

  // 1) batched MLP (M-tiled, byte-identical arithmetic to round 2)
  dim3 blk(256);
  for (int t = 0; t < NV / MT; ++t) {
    const float* embT = emb + (size_t)t * MT * EMB;
    float* logT = logit + (size_t)t * MT * NC;
    gemm_bias_act<<<dim3(EMB / TILE, MT / TILE), blk, 0, stream>>>(
        embT, W1, b1, H1t, MT, EMB, EMB, 1);
    gemm_bias_act<<<dim3(EMB / TILE, MT / TILE), blk, 0, stream>>>(
        H1t, W2, b2, H2t, MT, EMB, EMB, 1);
    gemm_bias_act<<<dim3((H3DIM + TILE - 1) / TILE, MT / TILE), blk, 0, stream>>>(
        H2t, W3, b3, H3t, MT, H3DIM, EMB, 1);
    gemm_bias_act<<<dim3(1, MT / TILE), blk, 0, stream>>>(
        H3t, W4, b4, logT, MT, NC, H3DIM, 0);
  }

  // 2) setup for dataflow phase (reuses dead GEMM-tile memory)
  init_kernel<<<NV / 256, 256, 0, stream>>>(col32, used, icnt);
  pos_kernel<<<NV / 256, 256, 0, stream>>>(ord, pos);
  yadd_kernel<<<(GROWS * NC + 255) / 256, 256, 0, stream>>>(logit, ord, y);

  // 3) dataflow coloring (critical path ~ DAG depth ~350, not 32768)
  color_dataflow<<<1024, 64, 0, stream>>>(y, adj, ord, pos, col32, used);

  // 4) parallel logp reconstruction + violations
  logp_kernel<<<8192, 256, 0, stream>>>(logit, adj, ord, pos, col32, term);
  violation_kernel<<<(NV * DEG) / 256, 256, 0, stream>>>(col32, adj, icnt + 1);
  sum_kernel<<<1, 256, 0, stream>>>(term, scal);

  // 5) outputs
  final_kernel<<<(NV + 1 + 255) / 256, 256, 0, stream>>>(col32, scal, used, icnt, out);
}

// Round 5
// 9267.701 us; speedup vs baseline: 11.3541x; 11.3541x over previous
//
#include <hip/hip_runtime.h>
#include <cstdint>
#include <cstddef>

#define NV    32768
#define EMB   512
#define DEG   32
#define NC    50
#define H3DIM 281
#define MT    4096
#define GROWS 32767            // N-1 gumbel rows
#define WGUARD (1u << 21)      // bounded spin: no infinite hang

// ---------------- threefry2x32, key = jax.random.key(42) -> (0, 42) ----------------
__device__ __forceinline__ void threefry(unsigned x0, unsigned x1,
                                         unsigned& y0, unsigned& y1) {
  const unsigned ks0 = 0u, ks1 = 42u, ks2 = 0x1BD11BDAu ^ 42u;
  x0 += ks0; x1 += ks1;
#define TFR(r) { x0 += x1; x1 = (x1 << (r)) | (x1 >> (32 - (r))); x1 ^= x0; }
  TFR(13) TFR(15) TFR(26) TFR(6)  x0 += ks1; x1 += ks2 + 1u;
  TFR(17) TFR(29) TFR(16) TFR(24) x0 += ks2; x1 += ks0 + 2u;
  TFR(13) TFR(15) TFR(26) TFR(6)  x0 += ks0; x1 += ks1 + 3u;
  TFR(17) TFR(29) TFR(16) TFR(24) x0 += ks1; x1 += ks2 + 4u;
  TFR(13) TFR(15) TFR(26) TFR(6)  x0 += ks2; x1 += ks0 + 5u;
#undef TFR
  y0 = x0; y1 = x1;
}

// partitionable threefry (jax >= 0.5 default): bits(i) = xor of threefry(key, (0, i))
__device__ __forceinline__ float gumbel_at(unsigned idx) {
  unsigned y0, y1;
  threefry(0u, idx, y0, y1);
  unsigned bits = y0 ^ y1;
  unsigned fb = (bits >> 9) | 0x3F800000u;
  float f = __uint_as_float(fb) - 1.0f;
  float u = fmaxf(f, 1.17549435e-38f);
  return -logf(-logf(u));
}

// ---------------- fp32 tiled GEMM: C = act(A[MxK] @ W[KxN] + b) ----------------
// k-ascending single-accumulator FMA chain — byte-identical across rounds
// (argmax exactness depends on stable logits bits).
#define TILE 64
#define BK   16
__global__ __launch_bounds__(256) void gemm_bias_act(
    const float* __restrict__ A, const float* __restrict__ W,
    const float* __restrict__ bias, float* __restrict__ C,
    int M, int N, int K, int act) {
  __shared__ float As[BK][TILE + 1];
  __shared__ float Bs[BK][TILE];
  int tid = threadIdx.x;
  int bm = blockIdx.y * TILE;
  int bn = blockIdx.x * TILE;
  int tx = tid & 15, ty = tid >> 4;
  int ar = tid >> 2;
  int ac = (tid & 3) * 4;
  int br = tid >> 4;
  int bc = (tid & 15) * 4;
  float acc[4][4] = {{0.f,0.f,0.f,0.f},{0.f,0.f,0.f,0.f},{0.f,0.f,0.f,0.f},{0.f,0.f,0.f,0.f}};

  for (int k0 = 0; k0 < K; k0 += BK) {
    {
      int gk = k0 + ac;
      const float* ap = A + (size_t)(bm + ar) * K + gk;
      float a0, a1, a2, a3;
      if (((K & 3) == 0) && (gk + 3 < K)) {
        float4 av = *(const float4*)ap;
        a0 = av.x; a1 = av.y; a2 = av.z; a3 = av.w;
      } else {
        a0 = (gk + 0 < K) ? ap[0] : 0.f;
        a1 = (gk + 1 < K) ? ap[1] : 0.f;
        a2 = (gk + 2 < K) ? ap[2] : 0.f;
        a3 = (gk + 3 < K) ? ap[3] : 0.f;
      }
      As[ac + 0][ar] = a0; As[ac + 1][ar] = a1;
      As[ac + 2][ar] = a2; As[ac + 3][ar] = a3;
    }
    {
      int gr = k0 + br;
      int gc = bn + bc;
      const float* bp = W + (size_t)gr * N + gc;
      float b0 = 0.f, b1 = 0.f, b2 = 0.f, b3 = 0.f;
      if (gr < K) {
        if (((N & 3) == 0) && (gc + 3 < N)) {
          float4 bv = *(const float4*)bp;
          b0 = bv.x; b1 = bv.y; b2 = bv.z; b3 = bv.w;
        } else {
          b0 = (gc + 0 < N) ? bp[0] : 0.f;
          b1 = (gc + 1 < N) ? bp[1] : 0.f;
          b2 = (gc + 2 < N) ? bp[2] : 0.f;
          b3 = (gc + 3 < N) ? bp[3] : 0.f;
        }
      }
      Bs[br][bc + 0] = b0; Bs[br][bc + 1] = b1;
      Bs[br][bc + 2] = b2; Bs[br][bc + 3] = b3;
    }
    __syncthreads();
#pragma unroll
    for (int kk = 0; kk < BK; ++kk) {
      float a[4], b[4];
#pragma unroll
      for (int i = 0; i < 4; ++i) a[i] = As[kk][ty * 4 + i];
#pragma unroll
      for (int j = 0; j < 4; ++j) b[j] = Bs[kk][tx * 4 + j];
#pragma unroll
      for (int i = 0; i < 4; ++i)
#pragma unroll
        for (int j = 0; j < 4; ++j)
          acc[i][j] = fmaf(a[i], b[j], acc[i][j]);
    }
    __syncthreads();
  }
#pragma unroll
  for (int i = 0; i < 4; ++i) {
    int row = bm + ty * 4 + i;
#pragma unroll
    for (int j = 0; j < 4; ++j) {
      int cn = bn + tx * 4 + j;
      if (cn < N) {
        float v = acc[i][j] + bias[cn];
        if (act) v = (v >= 0.f) ? v : 0.01f * v;
        C[(size_t)row * N + cn] = v;
      }
    }
  }
}

// ---------------- init ----------------
__global__ void init_kernel(int* __restrict__ colors,
                            unsigned long long* __restrict__ used,
                            int* __restrict__ icnt, int* __restrict__ Fptr) {
  int i = blockIdx.x * 256 + threadIdx.x;
  if (i < NV) colors[i] = -1;
  if (i == 0) { *used = 0ull; icnt[0] = 0; icnt[1] = 0; *Fptr = 0; }
}

// ---------------- inverse permutation ----------------
__global__ void pos_kernel(const int* __restrict__ order, int* __restrict__ pos) {
  int i = blockIdx.x * 256 + threadIdx.x;
  if (i < NV) pos[order[i]] = i;
}

// ---------------- mdp[p] = max position among earlier-neighbors (-1 if none) ----------------
__global__ __launch_bounds__(64) void mdp_kernel(const int* __restrict__ adj,
                                                 const int* __restrict__ order,
                                                 const int* __restrict__ pos,
                                                 int* __restrict__ mdp) {
  int p = blockIdx.x * 64 + threadIdx.x;
  int v = order[p];
  const int* arow = adj + (size_t)v * DEG;
  int m = -1;
#pragma unroll
  for (int j = 0; j < DEG; j += 4) {
    int4 u = *(const int4*)(arow + j);
    int q0 = pos[u.x], q1 = pos[u.y], q2 = pos[u.z], q3 = pos[u.w];
    if (q0 < p) m = max(m, q0);
    if (q1 < p) m = max(m, q1);
    if (q2 < p) m = max(m, q2);
    if (q3 < p) m = max(m, q3);
  }
  mdp[p] = m;
}

// ---------------- y[p][c] = logits[order[p]][c] + gumbel[(p-1)*NC + c] ----------------
__global__ void yadd_kernel(const float* __restrict__ logit,
                            const int* __restrict__ order,
                            float* __restrict__ y) {
  int tid = blockIdx.x * 256 + threadIdx.x;
  if (tid >= GROWS * NC) return;
  int p = tid / NC + 1;
  int c = tid - (p - 1) * NC;
  int v = order[p];
  y[p * NC + c] = logit[v * NC + c] + gumbel_at((unsigned)tid);
}

// ---------------- frontier-driven dataflow coloring ----------------
// Block 0: F-advancer (probes colors, publishes contiguous-done prefix F).
// Blocks 1..512: workers, ONE position per lane; readiness = register compare
// (mdp[p] < F). All loop memory ops are RELAXED device-scope (no cache
// invalidation — the round-3 21 GB refetch killer). The color word itself is
// the flag; visibility is data-carried through the coherence point.
__global__ __launch_bounds__(64) void color_dataflow2(
    const float* __restrict__ y, const int* __restrict__ adj,
    const int* __restrict__ order, const int* __restrict__ pos,
    const int* __restrict__ mdp, int* colors, int* Fptr,
    unsigned long long* used) {
  int lane = threadIdx.x;
  if (blockIdx.x == 0) {
    // ---- F advancer ----
    int F = 0;
    unsigned idle = 0;
    while (F < NV) {
      int i0 = F + lane;
      int c0 = (i0 < NV) ? __hip_atomic_load(colors + i0, __ATOMIC_RELAXED, __HIP_MEMORY_SCOPE_AGENT) : -1;
      int c1 = (i0 + 64 < NV) ? __hip_atomic_load(colors + i0 + 64, __ATOMIC_RELAXED, __HIP_MEMORY_SCOPE_AGENT) : -1;
      int c2 = (i0 + 128 < NV) ? __hip_atomic_load(colors + i0 + 128, __ATOMIC_RELAXED, __HIP_MEMORY_SCOPE_AGENT) : -1;
      int c3 = (i0 + 192 < NV) ? __hip_atomic_load(colors + i0 + 192, __ATOMIC_RELAXED, __HIP_MEMORY_SCOPE_AGENT) : -1;
      unsigned long long b0 = __ballot(c0 >= 0);
      unsigned long long b1 = __ballot(c1 >= 0);
      unsigned long long b2 = __ballot(c2 >= 0);
      unsigned long long b3 = __ballot(c3 >= 0);
      int adv;
      if (~b0)      adv = __ffsll(~b0) - 1;
      else if (~b1) adv = 64 + __ffsll(~b1) - 1;
      else if (~b2) adv = 128 + __ffsll(~b2) - 1;
      else if (~b3) adv = 192 + __ffsll(~b3) - 1;
      else          adv = 256;
      if (adv > 0) {
        F += adv;
        if (lane == 0)
          __hip_atomic_store(Fptr, F, __ATOMIC_RELAXED, __HIP_MEMORY_SCOPE_AGENT);
        idle = 0;
      } else {
        __builtin_amdgcn_s_sleep(1);
        if (++idle > WGUARD) break;  // halt guarantee
      }
    }
    return;
  }
  // ---- worker ----
  int p = (blockIdx.x - 1) * 64 + lane;  // one position per lane
  int v = order[p];
  int myMdp = mdp[p];
  bool done = false;
  unsigned long long um = 0ull;
  if (p == 0) {
    __hip_atomic_store(colors + v, 0, __ATOMIC_RELAXED, __HIP_MEMORY_SCOPE_AGENT);
    um = 1ull;
    done = true;
  }
  unsigned guard = 0;
  while (true) {
    // min mdp over pending lanes
    int m = done ? 0x7fffffff : myMdp;
#pragma unroll
    for (int off = 1; off < 64; off <<= 1) m = min(m, __shfl_xor(m, off));
    if (m == 0x7fffffff) break;  // all lanes done
    int F = __hip_atomic_load(Fptr, __ATOMIC_RELAXED, __HIP_MEMORY_SCOPE_AGENT);
    if (F <= m) {
      if (++guard > WGUARD) F = NV;  // halt guarantee: fire with what we have
      else {
        int gap = m + 1 - F;
        if (gap > 4096)      __builtin_amdgcn_s_sleep(64);
        else if (gap > 256)  __builtin_amdgcn_s_sleep(8);
        else                 __builtin_amdgcn_s_sleep(1);
        continue;
      }
    }
    if (!done && myMdp < F) {
      // all earlier-neighbors final: in-lane mask + masked argmax
      unsigned long long mask = 0ull;
      const int* arow = adj + (size_t)v * DEG;
#pragma unroll
      for (int j = 0; j < DEG; j += 4) {
        int4 u = *(const int4*)(arow + j);
        int q0 = pos[u.x], q1 = pos[u.y], q2 = pos[u.z], q3 = pos[u.w];
        if (q0 < p) { int c = __hip_atomic_load(colors + u.x, __ATOMIC_RELAXED, __HIP_MEMORY_SCOPE_AGENT); if (c >= 0) mask |= 1ull << c; }
        if (q1 < p) { int c = __hip_atomic_load(colors + u.y, __ATOMIC_RELAXED, __HIP_MEMORY_SCOPE_AGENT); if (c >= 0) mask |= 1ull << c; }
        if (q2 < p) { int c = __hip_atomic_load(colors + u.z, __ATOMIC_RELAXED, __HIP_MEMORY_SCOPE_AGENT); if (c >= 0) mask |= 1ull << c; }
        if (q3 < p) { int c = __hip_atomic_load(colors + u.w, __ATOMIC_RELAXED, __HIP_MEMORY_SCOPE_AGENT); if (c >= 0) mask |= 1ull << c; }
      }
      const float* yr = y + (size_t)p * NC;
      float best = -INFINITY;
      int bc = 0;
#pragma unroll
      for (int c = 0; c < NC; ++c) {
        float val = ((mask >> c) & 1ull) ? -INFINITY : yr[c];
        if (val > best) { best = val; bc = c; }  // strict >: first max, matches jnp.argmax
      }
      __hip_atomic_store(colors + v, bc, __ATOMIC_RELAXED, __HIP_MEMORY_SCOPE_AGENT);
      um |= 1ull << bc;
      done = true;
    }
  }
  // wave-OR of used-colors, one atomic per wave
#pragma unroll
  for (int off = 1; off < 64; off <<= 1) um |= __shfl_xor(um, off);
  if (lane == 0) atomicOr(used, um);
}

// ---------------- parallel logp reconstruction (one wave per position) ----------------
__global__ __launch_bounds__(256) void logp_kernel(
    const float* __restrict__ logit, const int* __restrict__ adj,
    const int* __restrict__ order, const int* __restrict__ pos,
    const int* __restrict__ colors, float* __restrict__ term) {
  int wid = blockIdx.x * 4 + (threadIdx.x >> 6);
  int lane = threadIdx.x & 63;
  int p = wid + 1;
  if (p >= NV) return;
  int v = order[p];
  int cchosen = colors[v];
  unsigned long long bits = 0ull;
  if (lane < DEG) {
    int u = adj[v * DEG + lane];
    if (pos[u] < p) bits = 1ull << colors[u];  // color at time p == final color
  }
#pragma unroll
  for (int off = 1; off < 64; off <<= 1) bits |= __shfl_xor(bits, off);
  bool masked = (bits >> lane) & 1ull;
  float xv = (lane < NC) ? logit[v * NC + lane] : -INFINITY;
  float x = (lane < NC && !masked) ? xv : -INFINITY;
  float xm = x;
#pragma unroll
  for (int off = 1; off < 64; off <<= 1) xm = fmaxf(xm, __shfl_xor(xm, off));
  float ex = expf(x - xm);
  float S = ex;
#pragma unroll
  for (int off = 1; off < 64; off <<= 1) S += __shfl_xor(S, off);
  float ec = __shfl(ex, cchosen);
  float pr = ec / S;
  if (lane == 0) term[p - 1] = logf(pr + 1e-8f) - logf(1e-8f);
}

// ---------------- deterministic sum of 32767 terms ----------------
__global__ __launch_bounds__(256) void sum_kernel(const float* __restrict__ term,
                                                  float* __restrict__ scal) {
  __shared__ float sm[256];
  float s = 0.f;
  for (int i = threadIdx.x; i < GROWS; i += 256) s += term[i];
  sm[threadIdx.x] = s;
  __syncthreads();
  for (int st = 128; st > 0; st >>= 1) {
    if (threadIdx.x < st) sm[threadIdx.x] += sm[threadIdx.x + st];
    __syncthreads();
  }
  if (threadIdx.x == 0) scal[0] = sm[0];
}

// ---------------- violation count ----------------
__global__ void violation_kernel(const int* __restrict__ col,
                                 const int* __restrict__ adj,
                                 int* __restrict__ cnt) {
  int idx = blockIdx.x * 256 + threadIdx.x;  // exactly NV*DEG threads
  int v = idx >> 5;
  int same = (col[adj[idx]] == col[v]) ? 1 : 0;
  unsigned long long b = __ballot(same);
  if ((threadIdx.x & 63) == 0) atomicAdd(cnt, __popcll(b));
}

// ---------------- write colors + loss ----------------
__global__ void final_kernel(const int* __restrict__ colors,
                             const float* __restrict__ scal,
                             const unsigned long long* __restrict__ used,
                             const int* __restrict__ icnt,
                             float* __restrict__ out) {
  int i = blockIdx.x * 256 + threadIdx.x;
  if (i < NV) out[i] = (float)colors[i];
  if (i == NV) {
    float logp = scal[0];
    float nused = (float)__popcll(*used);
    float ratio = (float)icnt[1] / 1048576.0f;  // exact: count / 2^20
    float cost = nused + ratio * 100.0f;
    out[NV] = cost * (logp / 32768.0f);
  }
}

// ---------------- launch ----------------
extern "C" void kernel_launch(void* const* d_in, const int* in_sizes, int n_in,
                              void* d_out, int out_size, void* d_ws, size_t ws_size,
                              hipStream_t stream) {
  const float* emb  = (const float*)d_in[0];
  const int*   adj  = (const int*)d_in[1];
  const int*   ord  = (const int*)d_in[2];
  const float* W1   = (const float*)d_in[3];
  const float* b1   = (const float*)d_in[4];
  const float* W2   = (const float*)d_in[5];
  const float* b2   = (const float*)d_in[6];
  const float* W3   = (const float*)d_in[7];
  const float* b3   = (const float*)d_in[8];
  const float* W4   = (const float*)d_in[9];
  const float* b4   = (const float*)d_in[10];
  float* out = (float*)d_out;

  // workspace (< 28 MB): GEMM tile buffers live only during the GEMM phase,
  // then their regions are reused for the dataflow state.
  char* ws = (char*)d_ws;
  const size_t MB = 1024 * 1024;
  float* logit = (float*)(ws);                    // 6.55 MB, lives whole run
  float* H1t   = (float*)(ws + 7 * MB);           // 8 MB (GEMM phase)
  float* H2t   = (float*)(ws + 15 * MB);          // 8 MB (GEMM phase)
  float* H3t   = (float*)(ws + 23 * MB);          // 4.6 MB (GEMM phase)
  float* y     = (float*)(ws + 7 * MB);           // 6.55 MB (reuses dead H1t)
  int*   col32 = (int*)  (ws + 15 * MB);                    // 128 KB (dead H2t)
  int*   pos   = (int*)  (ws + 15 * MB + 131072);           // 128 KB
  int*   mdpA  = (int*)  (ws + 15 * MB + 262144);           // 128 KB
  float* term  = (float*)(ws + 15 * MB + 393216);           // 128 KB
  float* scal  = (float*)(ws + 15 * MB + 524288);
  int*   Fptr  = (int*)  (ws + 15 * MB + 524288 + 64);
  unsigned long long* used = (unsigned long long*)(ws + 15 * MB + 524288 + 128);
  int*   icnt  = (int*)  (ws + 15 * MB + 524288 + 192);

  // 1) batched MLP (M-tiled; byte-identical arithmetic to rounds 2/3)
  dim3 blk(256);
  for (int t = 0; t < NV / MT; ++t) {
    const float* embT = emb + (size_t)t * MT * EMB;
    float* logT = logit + (size_t)t * MT * NC;
    gemm_bias_act<<<dim3(EMB / TILE, MT / TILE), blk, 0, stream>>>(
        embT, W1, b1, H1t, MT, EMB, EMB, 1);
    gemm_bias_act<<<dim3(EMB / TILE, MT / TILE), blk, 0, stream>>>(
        H1t, W2, b2, H2t, MT, EMB, EMB, 1);
    gemm_bias_act<<<dim3((H3DIM + TILE - 1) / TILE, MT / TILE), blk, 0, stream>>>(
        H2t, W3, b3, H3t, MT, H3DIM, EMB, 1);
    gemm_bias_act<<<dim3(1, MT / TILE), blk, 0, stream>>>(
        H3t, W4, b4, logT, MT, NC, H3DIM, 0);
  }

  // 2) dataflow-phase setup (reuses dead GEMM-tile memory)
  init_kernel<<<NV / 256, 256, 0, stream>>>(col32, used, icnt, Fptr);
  pos_kernel<<<NV / 256, 256, 0, stream>>>(ord, pos);
  mdp_kernel<<<NV / 64, 64, 0, stream>>>(adj, ord, pos, mdpA);
  yadd_kernel<<<(GROWS * NC + 255) / 256, 256, 0, stream>>>(logit, ord, y);

  // 3) frontier-driven dataflow coloring (1 advancer + 512 worker blocks)
  color_dataflow2<<<513, 64, 0, stream>>>(y, adj, ord, pos, mdpA, col32, Fptr, used);

  // 4) parallel logp reconstruction + violations
  logp_kernel<<<8192, 256, 0, stream>>>(logit, adj, ord, pos, col32, term);
  violation_kernel<<<(NV * DEG) / 256, 256, 0, stream>>>(col32, adj, icnt + 1);
  sum_kernel<<<1, 256, 0, stream>>>(term, scal);

  // 5) outputs
  final_kernel<<<(NV + 1 + 255) / 256, 256, 0, stream>>>(col32, scal, used, icnt, out);
}

// Round 6
// 3357.334 us; speedup vs baseline: 31.3423x; 2.7604x over previous
//
#include <hip/hip_runtime.h>
#include <cstdint>
#include <cstddef>

#define NV    32768
#define EMB   512
#define DEG   32
#define NC    50
#define H3DIM 281
#define MT    4096
#define GROWS 32767            // N-1 gumbel rows
#define WGUARD (1u << 20)      // bounded spin: no infinite hang

// ---------------- threefry2x32, key = jax.random.key(42) -> (0, 42) ----------------
__device__ __forceinline__ void threefry(unsigned x0, unsigned x1,
                                         unsigned& y0, unsigned& y1) {
  const unsigned ks0 = 0u, ks1 = 42u, ks2 = 0x1BD11BDAu ^ 42u;
  x0 += ks0; x1 += ks1;
#define TFR(r) { x0 += x1; x1 = (x1 << (r)) | (x1 >> (32 - (r))); x1 ^= x0; }
  TFR(13) TFR(15) TFR(26) TFR(6)  x0 += ks1; x1 += ks2 + 1u;
  TFR(17) TFR(29) TFR(16) TFR(24) x0 += ks2; x1 += ks0 + 2u;
  TFR(13) TFR(15) TFR(26) TFR(6)  x0 += ks0; x1 += ks1 + 3u;
  TFR(17) TFR(29) TFR(16) TFR(24) x0 += ks1; x1 += ks2 + 4u;
  TFR(13) TFR(15) TFR(26) TFR(6)  x0 += ks2; x1 += ks0 + 5u;
#undef TFR
  y0 = x0; y1 = x1;
}

// partitionable threefry (jax >= 0.5 default): bits(i) = xor of threefry(key, (0, i))
__device__ __forceinline__ float gumbel_at(unsigned idx) {
  unsigned y0, y1;
  threefry(0u, idx, y0, y1);
  unsigned bits = y0 ^ y1;
  unsigned fb = (bits >> 9) | 0x3F800000u;
  float f = __uint_as_float(fb) - 1.0f;
  float u = fmaxf(f, 1.17549435e-38f);
  return -logf(-logf(u));
}

// ---------------- 128x128 fp32 GEMM (M%128==0, K%16==0, N guarded) ----------------
// Per-output arithmetic: single accumulator, k-ascending fmaf, then +bias, leaky.
// BIT-IDENTICAL to the 64-tile kernel's outputs — tile shape only changes scheduling.
__global__ __launch_bounds__(256) void gemm128(
    const float* __restrict__ A, const float* __restrict__ W,
    const float* __restrict__ bias, float* __restrict__ C,
    int M, int N, int K, int act) {
  __shared__ float As[16][132];   // [k][m], padded
  __shared__ float Bs[16][128];   // [k][n]
  int tid = threadIdx.x;
  int bm = blockIdx.y * 128;
  int bn = blockIdx.x * 128;
  int tx = tid & 15, ty = tid >> 4;  // 16x16 threads, 8x8 micro-tile
  float acc[8][8];
#pragma unroll
  for (int i = 0; i < 8; ++i)
#pragma unroll
    for (int j = 0; j < 8; ++j) acc[i][j] = 0.f;

  for (int k0 = 0; k0 < K; k0 += 16) {
    // A tile: 128 rows x 16 k -> 512 float4, 2 per thread (transposed store)
#pragma unroll
    for (int l = 0; l < 2; ++l) {
      int idx = tid + l * 256;
      int row = idx >> 2, cc = (idx & 3) * 4;
      float4 av = *(const float4*)(A + (size_t)(bm + row) * K + (k0 + cc));
      As[cc + 0][row] = av.x; As[cc + 1][row] = av.y;
      As[cc + 2][row] = av.z; As[cc + 3][row] = av.w;
    }
    // B tile: 16 k-rows x 128 cols -> 512 float4, 2 per thread (N guarded)
#pragma unroll
    for (int l = 0; l < 2; ++l) {
      int idx = tid + l * 256;
      int row = idx >> 5, cc = (idx & 31) * 4;
      int gc = bn + cc;
      const float* bp = W + (size_t)(k0 + row) * N + gc;
      float4 bv;
      if (gc + 3 < N) bv = *(const float4*)bp;
      else {
        bv.x = (gc + 0 < N) ? bp[0] : 0.f;
        bv.y = (gc + 1 < N) ? bp[1] : 0.f;
        bv.z = (gc + 2 < N) ? bp[2] : 0.f;
        bv.w = (gc + 3 < N) ? bp[3] : 0.f;
      }
      *(float4*)&Bs[row][cc] = bv;
    }
    __syncthreads();
#pragma unroll
    for (int kk = 0; kk < 16; ++kk) {
      float a[8], b[8];
#pragma unroll
      for (int i = 0; i < 8; ++i) a[i] = As[kk][ty * 8 + i];
#pragma unroll
      for (int j = 0; j < 8; ++j) b[j] = Bs[kk][tx * 8 + j];
#pragma unroll
      for (int i = 0; i < 8; ++i)
#pragma unroll
        for (int j = 0; j < 8; ++j)
          acc[i][j] = fmaf(a[i], b[j], acc[i][j]);
    }
    __syncthreads();
  }
#pragma unroll
  for (int i = 0; i < 8; ++i) {
    int row = bm + ty * 8 + i;
#pragma unroll
    for (int j = 0; j < 8; ++j) {
      int cn = bn + tx * 8 + j;
      if (cn < N) {
        float v = acc[i][j] + bias[cn];
        if (act) v = (v >= 0.f) ? v : 0.01f * v;
        C[(size_t)row * N + cn] = v;
      }
    }
  }
}

// ---------------- 64-tile GEMM (kept for L4: K=281 not mult of 16, N=50) ----------------
#define TILE 64
#define BK   16
__global__ __launch_bounds__(256) void gemm_bias_act(
    const float* __restrict__ A, const float* __restrict__ W,
    const float* __restrict__ bias, float* __restrict__ C,
    int M, int N, int K, int act) {
  __shared__ float As[BK][TILE + 1];
  __shared__ float Bs[BK][TILE];
  int tid = threadIdx.x;
  int bm = blockIdx.y * TILE;
  int bn = blockIdx.x * TILE;
  int tx = tid & 15, ty = tid >> 4;
  int ar = tid >> 2;
  int ac = (tid & 3) * 4;
  int br = tid >> 4;
  int bc = (tid & 15) * 4;
  float acc[4][4] = {{0.f,0.f,0.f,0.f},{0.f,0.f,0.f,0.f},{0.f,0.f,0.f,0.f},{0.f,0.f,0.f,0.f}};

  for (int k0 = 0; k0 < K; k0 += BK) {
    {
      int gk = k0 + ac;
      const float* ap = A + (size_t)(bm + ar) * K + gk;
      float a0, a1, a2, a3;
      if (((K & 3) == 0) && (gk + 3 < K)) {
        float4 av = *(const float4*)ap;
        a0 = av.x; a1 = av.y; a2 = av.z; a3 = av.w;
      } else {
        a0 = (gk + 0 < K) ? ap[0] : 0.f;
        a1 = (gk + 1 < K) ? ap[1] : 0.f;
        a2 = (gk + 2 < K) ? ap[2] : 0.f;
        a3 = (gk + 3 < K) ? ap[3] : 0.f;
      }
      As[ac + 0][ar] = a0; As[ac + 1][ar] = a1;
      As[ac + 2][ar] = a2; As[ac + 3][ar] = a3;
    }
    {
      int gr = k0 + br;
      int gc = bn + bc;
      const float* bp = W + (size_t)gr * N + gc;
      float b0 = 0.f, b1 = 0.f, b2 = 0.f, b3 = 0.f;
      if (gr < K) {
        if (((N & 3) == 0) && (gc + 3 < N)) {
          float4 bv = *(const float4*)bp;
          b0 = bv.x; b1 = bv.y; b2 = bv.z; b3 = bv.w;
        } else {
          b0 = (gc + 0 < N) ? bp[0] : 0.f;
          b1 = (gc + 1 < N) ? bp[1] : 0.f;
          b2 = (gc + 2 < N) ? bp[2] : 0.f;
          b3 = (gc + 3 < N) ? bp[3] : 0.f;
        }
      }
      Bs[br][bc + 0] = b0; Bs[br][bc + 1] = b1;
      Bs[br][bc + 2] = b2; Bs[br][bc + 3] = b3;
    }
    __syncthreads();
#pragma unroll
    for (int kk = 0; kk < BK; ++kk) {
      float a[4], b[4];
#pragma unroll
      for (int i = 0; i < 4; ++i) a[i] = As[kk][ty * 4 + i];
#pragma unroll
      for (int j = 0; j < 4; ++j) b[j] = Bs[kk][tx * 4 + j];
#pragma unroll
      for (int i = 0; i < 4; ++i)
#pragma unroll
        for (int j = 0; j < 4; ++j)
          acc[i][j] = fmaf(a[i], b[j], acc[i][j]);
    }
    __syncthreads();
  }
#pragma unroll
  for (int i = 0; i < 4; ++i) {
    int row = bm + ty * 4 + i;
#pragma unroll
    for (int j = 0; j < 4; ++j) {
      int cn = bn + tx * 4 + j;
      if (cn < N) {
        float v = acc[i][j] + bias[cn];
        if (act) v = (v >= 0.f) ? v : 0.01f * v;
        C[(size_t)row * N + cn] = v;
      }
    }
  }
}

// ---------------- init ----------------
__global__ void init_kernel(int* __restrict__ colors,
                            unsigned long long* __restrict__ used,
                            int* __restrict__ icnt) {
  int i = blockIdx.x * 256 + threadIdx.x;
  if (i < NV) colors[i] = -1;
  if (i == 0) { *used = 0ull; icnt[0] = 0; icnt[1] = 0; }
}

// ---------------- inverse permutation ----------------
__global__ void pos_kernel(const int* __restrict__ order, int* __restrict__ pos) {
  int i = blockIdx.x * 256 + threadIdx.x;
  if (i < NV) pos[order[i]] = i;
}

// ---------------- y[p][c] = logits[order[p]][c] + gumbel[(p-1)*NC + c] ----------------
__global__ void yadd_kernel(const float* __restrict__ logit,
                            const int* __restrict__ order,
                            float* __restrict__ y) {
  int tid = blockIdx.x * 256 + threadIdx.x;
  if (tid >= GROWS * NC) return;
  int p = tid / NC + 1;
  int c = tid - (p - 1) * NC;
  int v = order[p];
  y[p * NC + c] = logit[v * NC + c] + gumbel_at((unsigned)tid);
}

// ---------------- true-dependency dataflow coloring ----------------
// One lane per position. Each lane holds its earlier-neighbor vertex list in
// registers and spins (RELAXED agent-scope — no invalidation) directly on
// those colors. Critical path = actual DAG depth (~350), each hop one
// store->IC->load round trip. No frontier, no hot word, no single advancer.
__global__ __launch_bounds__(64) void color_dataflow3(
    const float* __restrict__ y, const int* __restrict__ adj,
    const int* __restrict__ order, const int* __restrict__ pos,
    int* colors, unsigned long long* used) {
  int lane = threadIdx.x;
  int p = blockIdx.x * 64 + lane;     // position owned by this lane
  int v = order[p];
  int u[DEG];
  const int* arow = adj + (size_t)v * DEG;
#pragma unroll
  for (int j = 0; j < DEG; ++j) u[j] = arow[j];
  unsigned pend = 0;
#pragma unroll
  for (int j = 0; j < DEG; ++j)
    if (pos[u[j]] < p) pend |= 1u << j;

  unsigned long long colmask = 0ull;
  unsigned long long um = 0ull;
  bool done = false;
  if (p == 0) {
    __hip_atomic_store(colors + v, 0, __ATOMIC_RELAXED, __HIP_MEMORY_SCOPE_AGENT);
    um = 1ull; done = true; pend = 0;
  }
  unsigned guard = 0;
  while (true) {
    // poll all pending neighbor colors (independent masked loads, overlapped)
    unsigned newpend = pend;
#pragma unroll
    for (int j = 0; j < DEG; ++j) {
      if (pend & (1u << j)) {
        int c = __hip_atomic_load(colors + u[j], __ATOMIC_RELAXED, __HIP_MEMORY_SCOPE_AGENT);
        if (c >= 0) { colmask |= 1ull << c; newpend &= ~(1u << j); }
      }
    }
    pend = newpend;
    if (++guard > WGUARD) pend = 0;  // halt guarantee: fire with partial mask
    if (!done && pend == 0) {
      const float* yr = y + (size_t)p * NC;
      float best = -INFINITY;
      int bc = 0;
#pragma unroll
      for (int c = 0; c < NC; ++c) {
        float val = ((colmask >> c) & 1ull) ? -INFINITY : yr[c];
        if (val > best) { best = val; bc = c; }  // strict >: first max = jnp.argmax
      }
      __hip_atomic_store(colors + v, bc, __ATOMIC_RELAXED, __HIP_MEMORY_SCOPE_AGENT);
      um |= 1ull << bc;
      done = true;
    }
    if (__ballot(pend != 0) == 0ull) break;  // every lane in wave has fired
    __builtin_amdgcn_s_sleep(2);
  }
  // wave-OR of used-colors, one atomic per wave
#pragma unroll
  for (int off = 1; off < 64; off <<= 1) um |= __shfl_xor(um, off);
  if (lane == 0) atomicOr(used, um);
}

// ---------------- parallel logp reconstruction (one wave per position) ----------------
__global__ __launch_bounds__(256) void logp_kernel(
    const float* __restrict__ logit, const int* __restrict__ adj,
    const int* __restrict__ order, const int* __restrict__ pos,
    const int* __restrict__ colors, float* __restrict__ term) {
  int wid = blockIdx.x * 4 + (threadIdx.x >> 6);
  int lane = threadIdx.x & 63;
  int p = wid + 1;
  if (p >= NV) return;
  int v = order[p];
  int cchosen = colors[v];
  unsigned long long bits = 0ull;
  if (lane < DEG) {
    int u = adj[v * DEG + lane];
    if (pos[u] < p) bits = 1ull << colors[u];  // color at time p == final color
  }
#pragma unroll
  for (int off = 1; off < 64; off <<= 1) bits |= __shfl_xor(bits, off);
  bool masked = (bits >> lane) & 1ull;
  float xv = (lane < NC) ? logit[v * NC + lane] : -INFINITY;
  float x = (lane < NC && !masked) ? xv : -INFINITY;
  float xm = x;
#pragma unroll
  for (int off = 1; off < 64; off <<= 1) xm = fmaxf(xm, __shfl_xor(xm, off));
  float ex = expf(x - xm);
  float S = ex;
#pragma unroll
  for (int off = 1; off < 64; off <<= 1) S += __shfl_xor(S, off);
  float ec = __shfl(ex, cchosen);
  float pr = ec / S;
  if (lane == 0) term[p - 1] = logf(pr + 1e-8f) - logf(1e-8f);
}

// ---------------- deterministic sum of 32767 terms ----------------
__global__ __launch_bounds__(256) void sum_kernel(const float* __restrict__ term,
                                                  float* __restrict__ scal) {
  __shared__ float sm[256];
  float s = 0.f;
  for (int i = threadIdx.x; i < GROWS; i += 256) s += term[i];
  sm[threadIdx.x] = s;
  __syncthreads();
  for (int st = 128; st > 0; st >>= 1) {
    if (threadIdx.x < st) sm[threadIdx.x] += sm[threadIdx.x + st];
    __syncthreads();
  }
  if (threadIdx.x == 0) scal[0] = sm[0];
}

// ---------------- violation count ----------------
__global__ void violation_kernel(const int* __restrict__ col,
                                 const int* __restrict__ adj,
                                 int* __restrict__ cnt) {
  int idx = blockIdx.x * 256 + threadIdx.x;  // exactly NV*DEG threads
  int v = idx >> 5;
  int same = (col[adj[idx]] == col[v]) ? 1 : 0;
  unsigned long long b = __ballot(same);
  if ((threadIdx.x & 63) == 0) atomicAdd(cnt, __popcll(b));
}

// ---------------- write colors + loss ----------------
__global__ void final_kernel(const int* __restrict__ colors,
                             const float* __restrict__ scal,
                             const unsigned long long* __restrict__ used,
                             const int* __restrict__ icnt,
                             float* __restrict__ out) {
  int i = blockIdx.x * 256 + threadIdx.x;
  if (i < NV) out[i] = (float)colors[i];
  if (i == NV) {
    float logp = scal[0];
    float nused = (float)__popcll(*used);
    float ratio = (float)icnt[1] / 1048576.0f;  // exact: count / 2^20
    float cost = nused + ratio * 100.0f;
    out[NV] = cost * (logp / 32768.0f);
  }
}

// ---------------- launch ----------------
extern "C" void kernel_launch(void* const* d_in, const int* in_sizes, int n_in,
                              void* d_out, int out_size, void* d_ws, size_t ws_size,
                              hipStream_t stream) {
  const float* emb  = (const float*)d_in[0];
  const int*   adj  = (const int*)d_in[1];
  const int*   ord  = (const int*)d_in[2];
  const float* W1   = (const float*)d_in[3];
  const float* b1   = (const float*)d_in[4];
  const float* W2   = (const float*)d_in[5];
  const float* b2   = (const float*)d_in[6];
  const float* W3   = (const float*)d_in[7];
  const float* b3   = (const float*)d_in[8];
  const float* W4   = (const float*)d_in[9];
  const float* b4   = (const float*)d_in[10];
  float* out = (float*)d_out;

  // workspace (< 28 MB): GEMM tile buffers live only during the GEMM phase.
  char* ws = (char*)d_ws;
  const size_t MB = 1024 * 1024;
  float* logit = (float*)(ws);                    // 6.55 MB, lives whole run
  float* H1t   = (float*)(ws + 7 * MB);           // 8 MB (GEMM phase)
  float* H2t   = (float*)(ws + 15 * MB);          // 8 MB (GEMM phase)
  float* H3t   = (float*)(ws + 23 * MB);          // 4.6 MB (GEMM phase)
  float* y     = (float*)(ws + 7 * MB);           // 6.55 MB (reuses dead H1t)
  int*   col32 = (int*)  (ws + 15 * MB);                    // 128 KB (dead H2t)
  int*   pos   = (int*)  (ws + 15 * MB + 131072);           // 128 KB
  float* term  = (float*)(ws + 15 * MB + 262144);           // 128 KB
  float* scal  = (float*)(ws + 15 * MB + 458752);
  unsigned long long* used = (unsigned long long*)(ws + 15 * MB + 458752 + 64);
  int*   icnt  = (int*)  (ws + 15 * MB + 458752 + 128);

  // 1) batched MLP (M-tiled; per-element arithmetic bit-identical to rounds 2-5)
  dim3 blk(256);
  for (int t = 0; t < NV / MT; ++t) {
    const float* embT = emb + (size_t)t * MT * EMB;
    float* logT = logit + (size_t)t * MT * NC;
    gemm128<<<dim3(EMB / 128, MT / 128), blk, 0, stream>>>(
        embT, W1, b1, H1t, MT, EMB, EMB, 1);
    gemm128<<<dim3(EMB / 128, MT / 128), blk, 0, stream>>>(
        H1t, W2, b2, H2t, MT, EMB, EMB, 1);
    gemm128<<<dim3((H3DIM + 127) / 128, MT / 128), blk, 0, stream>>>(
        H2t, W3, b3, H3t, MT, H3DIM, EMB, 1);
    gemm_bias_act<<<dim3(1, MT / TILE), blk, 0, stream>>>(
        H3t, W4, b4, logT, MT, NC, H3DIM, 0);
  }

  // 2) dataflow-phase setup (reuses dead GEMM-tile memory)
  init_kernel<<<NV / 256, 256, 0, stream>>>(col32, used, icnt);
  pos_kernel<<<NV / 256, 256, 0, stream>>>(ord, pos);
  yadd_kernel<<<(GROWS * NC + 255) / 256, 256, 0, stream>>>(logit, ord, y);

  // 3) true-dependency dataflow coloring (512 waves, one lane per position)
  color_dataflow3<<<NV / 64, 64, 0, stream>>>(y, adj, ord, pos, col32, used);

  // 4) parallel logp reconstruction + violations
  logp_kernel<<<8192, 256, 0, stream>>>(logit, adj, ord, pos, col32, term);
  violation_kernel<<<(NV * DEG) / 256, 256, 0, stream>>>(col32, adj, icnt + 1);
  sum_kernel<<<1, 256, 0, stream>>>(term, scal);

  // 5) outputs
  final_kernel<<<(NV + 1 + 255) / 256, 256, 0, stream>>>(col32, scal, used, icnt, out);
}

// Round 7
// 1467.057 us; speedup vs baseline: 71.7264x; 2.2885x over previous
//
#include <hip/hip_runtime.h>
#include <cstdint>
#include <cstddef>

#define NV    32768
#define EMB   512
#define DEG   32
#define NC    50
#define H3DIM 281
#define GROWS 32767            // N-1 gumbel rows
#define WGUARD (1u << 20)      // bounded spin: no infinite hang

// ---------------- threefry2x32, key = jax.random.key(42) -> (0, 42) ----------------
__device__ __forceinline__ void threefry(unsigned x0, unsigned x1,
                                         unsigned& y0, unsigned& y1) {
  const unsigned ks0 = 0u, ks1 = 42u, ks2 = 0x1BD11BDAu ^ 42u;
  x0 += ks0; x1 += ks1;
#define TFR(r) { x0 += x1; x1 = (x1 << (r)) | (x1 >> (32 - (r))); x1 ^= x0; }
  TFR(13) TFR(15) TFR(26) TFR(6)  x0 += ks1; x1 += ks2 + 1u;
  TFR(17) TFR(29) TFR(16) TFR(24) x0 += ks2; x1 += ks0 + 2u;
  TFR(13) TFR(15) TFR(26) TFR(6)  x0 += ks0; x1 += ks1 + 3u;
  TFR(17) TFR(29) TFR(16) TFR(24) x0 += ks1; x1 += ks2 + 4u;
  TFR(13) TFR(15) TFR(26) TFR(6)  x0 += ks2; x1 += ks0 + 5u;
#undef TFR
  y0 = x0; y1 = x1;
}

// partitionable threefry (jax >= 0.5 default): bits(i) = xor of threefry(key, (0, i))
__device__ __forceinline__ float gumbel_at(unsigned idx) {
  unsigned y0, y1;
  threefry(0u, idx, y0, y1);
  unsigned bits = y0 ^ y1;
  unsigned fb = (bits >> 9) | 0x3F800000u;
  float f = __uint_as_float(fb) - 1.0f;
  float u = fmaxf(f, 1.17549435e-38f);
  return -logf(-logf(u));
}

// ---------------- 128x128 fp32 GEMM (M%128==0, K%16==0, N guarded) ----------------
// Per-output arithmetic: single accumulator, k-ascending fmaf, then +bias, leaky.
// Bit-identical for any M-tiling — only scheduling changes.
__global__ __launch_bounds__(256) void gemm128(
    const float* __restrict__ A, const float* __restrict__ W,
    const float* __restrict__ bias, float* __restrict__ C,
    int M, int N, int K, int act) {
  __shared__ float As[16][132];   // [k][m], padded
  __shared__ float Bs[16][128];   // [k][n]
  int tid = threadIdx.x;
  int bm = blockIdx.y * 128;
  int bn = blockIdx.x * 128;
  int tx = tid & 15, ty = tid >> 4;  // 16x16 threads, 8x8 micro-tile
  float acc[8][8];
#pragma unroll
  for (int i = 0; i < 8; ++i)
#pragma unroll
    for (int j = 0; j < 8; ++j) acc[i][j] = 0.f;

  for (int k0 = 0; k0 < K; k0 += 16) {
    // A tile: 128 rows x 16 k -> 512 float4, 2 per thread (transposed store)
#pragma unroll
    for (int l = 0; l < 2; ++l) {
      int idx = tid + l * 256;
      int row = idx >> 2, cc = (idx & 3) * 4;
      float4 av = *(const float4*)(A + (size_t)(bm + row) * K + (k0 + cc));
      As[cc + 0][row] = av.x; As[cc + 1][row] = av.y;
      As[cc + 2][row] = av.z; As[cc + 3][row] = av.w;
    }
    // B tile: 16 k-rows x 128 cols -> 512 float4, 2 per thread (N guarded)
#pragma unroll
    for (int l = 0; l < 2; ++l) {
      int idx = tid + l * 256;
      int row = idx >> 5, cc = (idx & 31) * 4;
      int gc = bn + cc;
      const float* bp = W + (size_t)(k0 + row) * N + gc;
      float4 bv;
      if (gc + 3 < N) bv = *(const float4*)bp;
      else {
        bv.x = (gc + 0 < N) ? bp[0] : 0.f;
        bv.y = (gc + 1 < N) ? bp[1] : 0.f;
        bv.z = (gc + 2 < N) ? bp[2] : 0.f;
        bv.w = (gc + 3 < N) ? bp[3] : 0.f;
      }
      *(float4*)&Bs[row][cc] = bv;
    }
    __syncthreads();
#pragma unroll
    for (int kk = 0; kk < 16; ++kk) {
      float a[8], b[8];
#pragma unroll
      for (int i = 0; i < 8; ++i) a[i] = As[kk][ty * 8 + i];
#pragma unroll
      for (int j = 0; j < 8; ++j) b[j] = Bs[kk][tx * 8 + j];
#pragma unroll
      for (int i = 0; i < 8; ++i)
#pragma unroll
        for (int j = 0; j < 8; ++j)
          acc[i][j] = fmaf(a[i], b[j], acc[i][j]);
    }
    __syncthreads();
  }
#pragma unroll
  for (int i = 0; i < 8; ++i) {
    int row = bm + ty * 8 + i;
#pragma unroll
    for (int j = 0; j < 8; ++j) {
      int cn = bn + tx * 8 + j;
      if (cn < N) {
        float v = acc[i][j] + bias[cn];
        if (act) v = (v >= 0.f) ? v : 0.01f * v;
        C[(size_t)row * N + cn] = v;
      }
    }
  }
}

// ---------------- 64-tile GEMM (kept for L4: K=281 not mult of 16, N=50) ----------------
#define TILE 64
#define BK   16
__global__ __launch_bounds__(256) void gemm_bias_act(
    const float* __restrict__ A, const float* __restrict__ W,
    const float* __restrict__ bias, float* __restrict__ C,
    int M, int N, int K, int act) {
  __shared__ float As[BK][TILE + 1];
  __shared__ float Bs[BK][TILE];
  int tid = threadIdx.x;
  int bm = blockIdx.y * TILE;
  int bn = blockIdx.x * TILE;
  int tx = tid & 15, ty = tid >> 4;
  int ar = tid >> 2;
  int ac = (tid & 3) * 4;
  int br = tid >> 4;
  int bc = (tid & 15) * 4;
  float acc[4][4] = {{0.f,0.f,0.f,0.f},{0.f,0.f,0.f,0.f},{0.f,0.f,0.f,0.f},{0.f,0.f,0.f,0.f}};

  for (int k0 = 0; k0 < K; k0 += BK) {
    {
      int gk = k0 + ac;
      const float* ap = A + (size_t)(bm + ar) * K + gk;
      float a0, a1, a2, a3;
      if (((K & 3) == 0) && (gk + 3 < K)) {
        float4 av = *(const float4*)ap;
        a0 = av.x; a1 = av.y; a2 = av.z; a3 = av.w;
      } else {
        a0 = (gk + 0 < K) ? ap[0] : 0.f;
        a1 = (gk + 1 < K) ? ap[1] : 0.f;
        a2 = (gk + 2 < K) ? ap[2] : 0.f;
        a3 = (gk + 3 < K) ? ap[3] : 0.f;
      }
      As[ac + 0][ar] = a0; As[ac + 1][ar] = a1;
      As[ac + 2][ar] = a2; As[ac + 3][ar] = a3;
    }
    {
      int gr = k0 + br;
      int gc = bn + bc;
      const float* bp = W + (size_t)gr * N + gc;
      float b0 = 0.f, b1 = 0.f, b2 = 0.f, b3 = 0.f;
      if (gr < K) {
        if (((N & 3) == 0) && (gc + 3 < N)) {
          float4 bv = *(const float4*)bp;
          b0 = bv.x; b1 = bv.y; b2 = bv.z; b3 = bv.w;
        } else {
          b0 = (gc + 0 < N) ? bp[0] : 0.f;
          b1 = (gc + 1 < N) ? bp[1] : 0.f;
          b2 = (gc + 2 < N) ? bp[2] : 0.f;
          b3 = (gc + 3 < N) ? bp[3] : 0.f;
        }
      }
      Bs[br][bc + 0] = b0; Bs[br][bc + 1] = b1;
      Bs[br][bc + 2] = b2; Bs[br][bc + 3] = b3;
    }
    __syncthreads();
#pragma unroll
    for (int kk = 0; kk < BK; ++kk) {
      float a[4], b[4];
#pragma unroll
      for (int i = 0; i < 4; ++i) a[i] = As[kk][ty * 4 + i];
#pragma unroll
      for (int j = 0; j < 4; ++j) b[j] = Bs[kk][tx * 4 + j];
#pragma unroll
      for (int i = 0; i < 4; ++i)
#pragma unroll
        for (int j = 0; j < 4; ++j)
          acc[i][j] = fmaf(a[i], b[j], acc[i][j]);
    }
    __syncthreads();
  }
#pragma unroll
  for (int i = 0; i < 4; ++i) {
    int row = bm + ty * 4 + i;
#pragma unroll
    for (int j = 0; j < 4; ++j) {
      int cn = bn + tx * 4 + j;
      if (cn < N) {
        float v = acc[i][j] + bias[cn];
        if (act) v = (v >= 0.f) ? v : 0.01f * v;
        C[(size_t)row * N + cn] = v;
      }
    }
  }
}

// ---------------- init ----------------
__global__ void init_kernel(int* __restrict__ colors,
                            unsigned long long* __restrict__ used,
                            int* __restrict__ icnt) {
  int i = blockIdx.x * 256 + threadIdx.x;
  if (i < NV) colors[i] = -1;
  if (i == 0) { *used = 0ull; icnt[0] = 0; icnt[1] = 0; }
}

// ---------------- inverse permutation ----------------
__global__ void pos_kernel(const int* __restrict__ order, int* __restrict__ pos) {
  int i = blockIdx.x * 256 + threadIdx.x;
  if (i < NV) pos[order[i]] = i;
}

// ---------------- y[p][c] = logits[order[p]][c] + gumbel[(p-1)*NC + c] ----------------
__global__ void yadd_kernel(const float* __restrict__ logit,
                            const int* __restrict__ order,
                            float* __restrict__ y) {
  int tid = blockIdx.x * 256 + threadIdx.x;
  if (tid >= GROWS * NC) return;
  int p = tid / NC + 1;
  int c = tid - (p - 1) * NC;
  int v = order[p];
  y[p * NC + c] = logit[v * NC + c] + gumbel_at((unsigned)tid);
}

// ---------------- true-dependency dataflow coloring ----------------
// One lane per position; spins (RELAXED agent-scope) directly on its own
// earlier-neighbor colors held in registers. Critical path = DAG depth ~350.
__global__ __launch_bounds__(64) void color_dataflow3(
    const float* __restrict__ y, const int* __restrict__ adj,
    const int* __restrict__ order, const int* __restrict__ pos,
    int* colors, unsigned long long* used) {
  int lane = threadIdx.x;
  int p = blockIdx.x * 64 + lane;     // position owned by this lane
  int v = order[p];
  int u[DEG];
  const int* arow = adj + (size_t)v * DEG;
#pragma unroll
  for (int j = 0; j < DEG; ++j) u[j] = arow[j];
  unsigned pend = 0;
#pragma unroll
  for (int j = 0; j < DEG; ++j)
    if (pos[u[j]] < p) pend |= 1u << j;

  unsigned long long colmask = 0ull;
  unsigned long long um = 0ull;
  bool done = false;
  if (p == 0) {
    __hip_atomic_store(colors + v, 0, __ATOMIC_RELAXED, __HIP_MEMORY_SCOPE_AGENT);
    um = 1ull; done = true; pend = 0;
  }
  unsigned guard = 0;
  while (true) {
    unsigned newpend = pend;
#pragma unroll
    for (int j = 0; j < DEG; ++j) {
      if (pend & (1u << j)) {
        int c = __hip_atomic_load(colors + u[j], __ATOMIC_RELAXED, __HIP_MEMORY_SCOPE_AGENT);
        if (c >= 0) { colmask |= 1ull << c; newpend &= ~(1u << j); }
      }
    }
    pend = newpend;
    if (++guard > WGUARD) pend = 0;  // halt guarantee: fire with partial mask
    if (!done && pend == 0) {
      const float* yr = y + (size_t)p * NC;
      float best = -INFINITY;
      int bc = 0;
#pragma unroll
      for (int c = 0; c < NC; ++c) {
        float val = ((colmask >> c) & 1ull) ? -INFINITY : yr[c];
        if (val > best) { best = val; bc = c; }  // strict >: first max = jnp.argmax
      }
      __hip_atomic_store(colors + v, bc, __ATOMIC_RELAXED, __HIP_MEMORY_SCOPE_AGENT);
      um |= 1ull << bc;
      done = true;
    }
    if (__ballot(pend != 0) == 0ull) break;  // every lane in wave has fired
    __builtin_amdgcn_s_sleep(2);
  }
#pragma unroll
  for (int off = 1; off < 64; off <<= 1) um |= __shfl_xor(um, off);
  if (lane == 0) atomicOr(used, um);
}

// ---------------- parallel logp reconstruction (one wave per position) ----------------
__global__ __launch_bounds__(256) void logp_kernel(
    const float* __restrict__ logit, const int* __restrict__ adj,
    const int* __restrict__ order, const int* __restrict__ pos,
    const int* __restrict__ colors, float* __restrict__ term) {
  int wid = blockIdx.x * 4 + (threadIdx.x >> 6);
  int lane = threadIdx.x & 63;
  int p = wid + 1;
  if (p >= NV) return;
  int v = order[p];
  int cchosen = colors[v];
  unsigned long long bits = 0ull;
  if (lane < DEG) {
    int u = adj[v * DEG + lane];
    if (pos[u] < p) bits = 1ull << colors[u];  // color at time p == final color
  }
#pragma unroll
  for (int off = 1; off < 64; off <<= 1) bits |= __shfl_xor(bits, off);
  bool masked = (bits >> lane) & 1ull;
  float xv = (lane < NC) ? logit[v * NC + lane] : -INFINITY;
  float x = (lane < NC && !masked) ? xv : -INFINITY;
  float xm = x;
#pragma unroll
  for (int off = 1; off < 64; off <<= 1) xm = fmaxf(xm, __shfl_xor(xm, off));
  float ex = expf(x - xm);
  float S = ex;
#pragma unroll
  for (int off = 1; off < 64; off <<= 1) S += __shfl_xor(S, off);
  float ec = __shfl(ex, cchosen);
  float pr = ec / S;
  if (lane == 0) term[p - 1] = logf(pr + 1e-8f) - logf(1e-8f);
}

// ---------------- deterministic sum of 32767 terms ----------------
__global__ __launch_bounds__(256) void sum_kernel(const float* __restrict__ term,
                                                  float* __restrict__ scal) {
  __shared__ float sm[256];
  float s = 0.f;
  for (int i = threadIdx.x; i < GROWS; i += 256) s += term[i];
  sm[threadIdx.x] = s;
  __syncthreads();
  for (int st = 128; st > 0; st >>= 1) {
    if (threadIdx.x < st) sm[threadIdx.x] += sm[threadIdx.x + st];
    __syncthreads();
  }
  if (threadIdx.x == 0) scal[0] = sm[0];
}

// ---------------- violation count ----------------
__global__ void violation_kernel(const int* __restrict__ col,
                                 const int* __restrict__ adj,
                                 int* __restrict__ cnt) {
  int idx = blockIdx.x * 256 + threadIdx.x;  // exactly NV*DEG threads
  int v = idx >> 5;
  int same = (col[adj[idx]] == col[v]) ? 1 : 0;
  unsigned long long b = __ballot(same);
  if ((threadIdx.x & 63) == 0) atomicAdd(cnt, __popcll(b));
}

// ---------------- write colors + loss ----------------
__global__ void final_kernel(const int* __restrict__ colors,
                             const float* __restrict__ scal,
                             const unsigned long long* __restrict__ used,
                             const int* __restrict__ icnt,
                             float* __restrict__ out) {
  int i = blockIdx.x * 256 + threadIdx.x;
  if (i < NV) out[i] = (float)colors[i];
  if (i == NV) {
    float logp = scal[0];
    float nused = (float)__popcll(*used);
    float ratio = (float)icnt[1] / 1048576.0f;  // exact: count / 2^20
    float cost = nused + ratio * 100.0f;
    out[NV] = cost * (logp / 32768.0f);
  }
}

// ---------------- launch ----------------
extern "C" void kernel_launch(void* const* d_in, const int* in_sizes, int n_in,
                              void* d_out, int out_size, void* d_ws, size_t ws_size,
                              hipStream_t stream) {
  const float* emb  = (const float*)d_in[0];
  const int*   adj  = (const int*)d_in[1];
  const int*   ord  = (const int*)d_in[2];
  const float* W1   = (const float*)d_in[3];
  const float* b1   = (const float*)d_in[4];
  const float* W2   = (const float*)d_in[5];
  const float* b2   = (const float*)d_in[6];
  const float* W3   = (const float*)d_in[7];
  const float* b3   = (const float*)d_in[8];
  const float* W4   = (const float*)d_in[9];
  const float* b4   = (const float*)d_in[10];
  float* out = (float*)d_out;

  const size_t MB = 1024 * 1024;
  // Pick M-tile from ws_size (constant across calls -> graph-capture safe).
  // Per-row GEMM arithmetic is independent of MT -> bit-identical logits.
  int mt;
  if (ws_size >= 138 * MB)      mt = 32768;  // full-M: 1024-block grids, 4 dispatches
  else if (ws_size >= 51 * MB)  mt = 8192;   // 256-block grids
  else                          mt = 4096;   // proven-fit fallback (28 MB)

  char* ws = (char*)d_ws;
  size_t h1b = (size_t)mt * EMB * 4;          // H1 tile bytes
  float* logit = (float*)(ws);                // 6.55 MB, lives whole run
  float* H1t   = (float*)(ws + 7 * MB);
  float* H2t   = (float*)(ws + 7 * MB + h1b);
  float* H3t   = (float*)(ws + 7 * MB + 2 * h1b);
  // after GEMMs: y overlays dead H1t; small state overlays dead H2t
  float* y     = (float*)(ws + 7 * MB);
  char*  sb    = ws + 7 * MB + h1b;
  int*   col32 = (int*)  (sb);                 // 128 KB
  int*   pos   = (int*)  (sb + 131072);        // 128 KB
  float* term  = (float*)(sb + 262144);        // 128 KB
  float* scal  = (float*)(sb + 458752);
  unsigned long long* used = (unsigned long long*)(sb + 458752 + 64);
  int*   icnt  = (int*)  (sb + 458752 + 128);

  // 1) batched MLP (per-element arithmetic bit-identical to rounds 2-6)
  dim3 blk(256);
  for (int t = 0; t < NV / mt; ++t) {
    const float* embT = emb + (size_t)t * mt * EMB;
    float* logT = logit + (size_t)t * mt * NC;
    gemm128<<<dim3(EMB / 128, mt / 128), blk, 0, stream>>>(
        embT, W1, b1, H1t, mt, EMB, EMB, 1);
    gemm128<<<dim3(EMB / 128, mt / 128), blk, 0, stream>>>(
        H1t, W2, b2, H2t, mt, EMB, EMB, 1);
    gemm128<<<dim3((H3DIM + 127) / 128, mt / 128), blk, 0, stream>>>(
        H2t, W3, b3, H3t, mt, H3DIM, EMB, 1);
    gemm_bias_act<<<dim3(1, mt / TILE), blk, 0, stream>>>(
        H3t, W4, b4, logT, mt, NC, H3DIM, 0);
  }

  // 2) dataflow-phase setup (reuses dead GEMM-tile memory)
  init_kernel<<<NV / 256, 256, 0, stream>>>(col32, used, icnt);
  pos_kernel<<<NV / 256, 256, 0, stream>>>(ord, pos);
  yadd_kernel<<<(GROWS * NC + 255) / 256, 256, 0, stream>>>(logit, ord, y);

  // 3) true-dependency dataflow coloring (512 waves, one lane per position)
  color_dataflow3<<<NV / 64, 64, 0, stream>>>(y, adj, ord, pos, col32, used);

  // 4) parallel logp reconstruction + violations
  logp_kernel<<<8192, 256, 0, stream>>>(logit, adj, ord, pos, col32, term);
  violation_kernel<<<(NV * DEG) / 256, 256, 0, stream>>>(col32, adj, icnt + 1);
  sum_kernel<<<1, 256, 0, stream>>>(term, scal);

  // 5) outputs
  final_kernel<<<(NV + 1 + 255) / 256, 256, 0, stream>>>(col32, scal, used, icnt, out);
}